// Round 10
// baseline (1072.559 us; speedup 1.0000x reference)
//
#include <hip/hip_runtime.h>
#include <hip/hip_bf16.h>

// MLP 4096x2048 -> [4096,4096,4096,1024], fp32 in/out.
// bf16x3 split GEMM (A*W ~= Ah*Wh + Ah*Wl + Al*Wh) on mfma_f32_16x16x32_bf16.
// 256x256 tile, BK=32, 8 waves. ONE barrier-free compute region per K-tile:
// 24 front-loaded ds_read_b128 + 96 MFMA overlap via compiler-progressive
// lgkmcnt (pipes overlap across skewed waves); counted vmcnt double-buffer
// (T4), setprio (T5), XOR LDS swizzle (T2, measured 0 conflicts), XCD swizzle
// (T1). 2 barriers/K-tile. L3 (N=1024): split-K=4 + reduce.

typedef __attribute__((ext_vector_type(4))) float f32x4;
typedef __attribute__((ext_vector_type(8))) short bf16x8;
typedef __attribute__((ext_vector_type(4))) unsigned short us4;

#define LDS_AS __attribute__((address_space(3)))
#define GLB_AS __attribute__((address_space(1)))

static __device__ __forceinline__ unsigned short f2bf(float f) {
    union { float f; unsigned int u; } x; x.f = f;
    unsigned int r = (x.u + 0x7FFFu + ((x.u >> 16) & 1u)) >> 16;  // RNE
    return (unsigned short)r;
}
static __device__ __forceinline__ float bf2f(unsigned short u) {
    union { float f; unsigned int u; } x; x.u = ((unsigned int)u) << 16;
    return x.f;
}

// ---------------- fp32 -> (bf16 hi, bf16 lo) split ----------------
__global__ void split_kernel(const float* __restrict__ src,
                             unsigned short* __restrict__ hi,
                             unsigned short* __restrict__ lo, int n4) {
    int i = blockIdx.x * 256 + threadIdx.x;
    if (i >= n4) return;
    f32x4 v = ((const f32x4*)src)[i];
    us4 h, l;
#pragma unroll
    for (int j = 0; j < 4; ++j) {
        unsigned short hb = f2bf(v[j]);
        h[j] = hb;
        l[j] = f2bf(v[j] - bf2f(hb));
    }
    ((us4*)hi)[i] = h;
    ((us4*)lo)[i] = l;
}

// ---------------- split-K reduce: out = sum(partials) + bias ----------------
__global__ void reduce4_bias(const float* __restrict__ part,
                             const float* __restrict__ bias,
                             float* __restrict__ out, int n4, int N, size_t stride) {
    int i = blockIdx.x * 256 + threadIdx.x;
    if (i >= n4) return;
    f32x4 v = ((const f32x4*)part)[i];
    v += ((const f32x4*)(part + stride))[i];
    v += ((const f32x4*)(part + 2 * stride))[i];
    v += ((const f32x4*)(part + 3 * stride))[i];
    f32x4 b = *(const f32x4*)&bias[(i * 4) & (N - 1)];
    ((f32x4*)out)[i] = v + b;
}

// ================= 256x256 split GEMM, 2 barriers per K-tile =================
// LDS: buffer b (b=0,1) at b*32768 ushorts; tiles: 0=Ahi 1=Alo 2=Whi 3=Wlo,
// each [256][32] ushort (8192). Swizzle: slot s of row holds K-chunk s^((row>>1)&3).
// Ks = row stride (full K), Kl = K elements per block.
// KSPLIT=4: wg -> (tile, kchunk); A/W offset kc*Kl; Cf offset kc*M*N.
template <int RELU, int SPLIT_OUT, int BIAS, int KSPLIT>
__global__ __launch_bounds__(512, 2) void gemm256(
    const unsigned short* __restrict__ Ahi, const unsigned short* __restrict__ Alo,
    const unsigned short* __restrict__ Whi, const unsigned short* __restrict__ Wlo,
    const float* __restrict__ bias,
    float* __restrict__ Cf,
    unsigned short* __restrict__ Chi, unsigned short* __restrict__ Clo,
    int M, int N, int Ks, int Kl) {
    extern __shared__ unsigned short lds[];

    const int tid = threadIdx.x;
    const int lane = tid & 63;
    const int wave = tid >> 6;
    const int wr = wave >> 2;   // 0..1 : 128-row block
    const int wc = wave & 3;    // 0..3 : 64-col block
    const int r15 = lane & 15;
    const int kb = lane >> 4;   // 0..3 : 16B K-slot

    // XCD-aware bijective block swizzle (grid=256, %8==0)
    int wg = blockIdx.x;
    const int cpx = gridDim.x >> 3;
    wg = (wg & 7) * cpx + (wg >> 3);
    int kc = 0;
    if constexpr (KSPLIT == 4) { kc = wg & 3; wg >>= 2; }
    const int nbn = N >> 8;
    const int bm = (wg / nbn) << 8;
    const int bn = (wg % nbn) << 8;
    const int koff = kc * Kl;

    // staging map: 2 chunks/thread/tile; chunk c -> row c>>2, slot c&3,
    // source K-chunk (c&3)^((row>>1)&3); LDS dest linear at c*16B.
    const int r0 = tid >> 2;
    const int s0 = (tid & 3) ^ ((r0 >> 1) & 3);
    const int c1 = tid + 512;
    const int r1 = c1 >> 2;
    const int s1 = (c1 & 3) ^ ((r1 >> 1) & 3);

    f32x4 acc[8][4];
#pragma unroll
    for (int i = 0; i < 8; ++i)
#pragma unroll
        for (int j = 0; j < 4; ++j) acc[i][j] = (f32x4){0.f, 0.f, 0.f, 0.f};

    const int nkt = Kl >> 5;

    auto issue = [&](const unsigned short* __restrict__ G, int R0, int k0,
                     int buf, int tile) {
        unsigned short* dst = lds + buf * 32768 + tile * 8192;
        __builtin_amdgcn_global_load_lds(
            (const GLB_AS void*)(G + (size_t)(R0 + r0) * Ks + koff + k0 + s0 * 8),
            (LDS_AS void*)(dst + tid * 8), 16, 0, 0);
        __builtin_amdgcn_global_load_lds(
            (const GLB_AS void*)(G + (size_t)(R0 + r1) * Ks + koff + k0 + s1 * 8),
            (LDS_AS void*)(dst + c1 * 8), 16, 0, 0);
    };

    // prologue: t=0 all 4 tiles (8 loads) + t=1 A tiles (4 loads);
    // vmcnt(4) => t=0 landed; t=1 A still in flight.
    issue(Ahi, bm, 0, 0, 0);
    issue(Alo, bm, 0, 0, 1);
    issue(Whi, bn, 0, 0, 2);
    issue(Wlo, bn, 0, 0, 3);
    issue(Ahi, bm, 32, 1, 0);
    issue(Alo, bm, 32, 1, 1);
    asm volatile("s_waitcnt vmcnt(4)" ::: "memory");
    __builtin_amdgcn_s_barrier();
    asm volatile("" ::: "memory");

    bf16x8 a_[4][2], a2_[4][2], w_[4][2];

    for (int t = 0; t < nkt; ++t) {
        const int cur = t & 1, nxt = cur ^ 1;
        const unsigned short* base = lds + cur * 32768;
        const int k1 = (t + 1) << 5;

        // ---- front-load ALL fragment reads of buf[cur] (24 x ds_read_b128) ----
#pragma unroll
        for (int i = 0; i < 4; ++i) {
            const int row = wr * 128 + i * 16 + r15;
            const int us = kb ^ ((row >> 1) & 3);
            a_[i][0] = *(const bf16x8*)(base + 0 * 8192 + row * 32 + us * 8);
            a_[i][1] = *(const bf16x8*)(base + 1 * 8192 + row * 32 + us * 8);
        }
#pragma unroll
        for (int j = 0; j < 4; ++j) {
            const int row = wc * 64 + j * 16 + r15;
            const int us = kb ^ ((row >> 1) & 3);
            w_[j][0] = *(const bf16x8*)(base + 2 * 8192 + row * 32 + us * 8);
            w_[j][1] = *(const bf16x8*)(base + 3 * 8192 + row * 32 + us * 8);
        }
#pragma unroll
        for (int i = 0; i < 4; ++i) {
            const int row = wr * 128 + (4 + i) * 16 + r15;
            const int us = kb ^ ((row >> 1) & 3);
            a2_[i][0] = *(const bf16x8*)(base + 0 * 8192 + row * 32 + us * 8);
            a2_[i][1] = *(const bf16x8*)(base + 1 * 8192 + row * 32 + us * 8);
        }
        // issue W(t+1) early: lands under this tile's MFMA shadow
        if (t + 1 < nkt) {
            issue(Whi, bn, k1, nxt, 2);
            issue(Wlo, bn, k1, nxt, 3);
        }

        // ---- one 96-MFMA region; compiler-progressive lgkmcnt overlaps the
        //      LDS drain with MFMA issue; waves skew freely (no barrier) ----
        __builtin_amdgcn_s_setprio(1);
#pragma unroll
        for (int j = 0; j < 4; ++j)
#pragma unroll
            for (int i = 0; i < 4; ++i) {
                acc[i][j] = __builtin_amdgcn_mfma_f32_16x16x32_bf16(a_[i][0], w_[j][0], acc[i][j], 0, 0, 0);
                acc[i][j] = __builtin_amdgcn_mfma_f32_16x16x32_bf16(a_[i][0], w_[j][1], acc[i][j], 0, 0, 0);
                acc[i][j] = __builtin_amdgcn_mfma_f32_16x16x32_bf16(a_[i][1], w_[j][0], acc[i][j], 0, 0, 0);
            }
#pragma unroll
        for (int j = 0; j < 4; ++j)
#pragma unroll
            for (int i = 0; i < 4; ++i) {
                acc[4 + i][j] = __builtin_amdgcn_mfma_f32_16x16x32_bf16(a2_[i][0], w_[j][0], acc[4 + i][j], 0, 0, 0);
                acc[4 + i][j] = __builtin_amdgcn_mfma_f32_16x16x32_bf16(a2_[i][0], w_[j][1], acc[4 + i][j], 0, 0, 0);
                acc[4 + i][j] = __builtin_amdgcn_mfma_f32_16x16x32_bf16(a2_[i][1], w_[j][0], acc[4 + i][j], 0, 0, 0);
            }
        __builtin_amdgcn_s_setprio(0);

        // ---- fence: all buf[cur] reads done -> A(t+2) may overwrite it ----
        asm volatile("s_waitcnt lgkmcnt(0)" ::: "memory");
        __builtin_amdgcn_s_barrier();
        if (t + 2 < nkt) {
            const int k2 = (t + 2) << 5;
            issue(Ahi, bm, k2, cur, 0);
            issue(Alo, bm, k2, cur, 1);
        }

        // ---- boundary: counted wait (never 0 mid-loop); buf[nxt] ready ----
        if (t + 1 < nkt) {
            if (t + 2 < nkt) asm volatile("s_waitcnt vmcnt(4)" ::: "memory");
            else             asm volatile("s_waitcnt vmcnt(0)" ::: "memory");
        }
        __builtin_amdgcn_s_barrier();
        asm volatile("" ::: "memory");
    }

    // epilogue; C/D map: col=lane&15, row=(lane>>4)*4+reg
    if constexpr (KSPLIT == 4) Cf += (size_t)kc * ((size_t)M * N);
    float bv[4];
    if constexpr (BIAS) {
#pragma unroll
        for (int j = 0; j < 4; ++j) bv[j] = bias[bn + wc * 64 + j * 16 + r15];
    } else {
#pragma unroll
        for (int j = 0; j < 4; ++j) bv[j] = 0.f;
    }
#pragma unroll
    for (int i = 0; i < 8; ++i) {
#pragma unroll
        for (int j = 0; j < 4; ++j) {
            const int colg = bn + wc * 64 + j * 16 + r15;
#pragma unroll
            for (int r = 0; r < 4; ++r) {
                const int rowg = bm + wr * 128 + i * 16 + kb * 4 + r;
                float v = acc[i][j][r] + bv[j];
                if (RELU) v = v > 0.f ? v : 0.f;
                if constexpr (SPLIT_OUT) {
                    unsigned short h = f2bf(v);
                    Chi[(size_t)rowg * N + colg] = h;
                    Clo[(size_t)rowg * N + colg] = f2bf(v - bf2f(h));
                } else {
                    Cf[(size_t)rowg * N + colg] = v;
                }
            }
        }
    }
}

extern "C" void kernel_launch(void* const* d_in, const int* in_sizes, int n_in,
                              void* d_out, int out_size, void* d_ws, size_t ws_size,
                              hipStream_t stream) {
    const float* x  = (const float*)d_in[0];
    const float* W0 = (const float*)d_in[1];
    const float* b0 = (const float*)d_in[2];
    const float* W1 = (const float*)d_in[3];
    const float* b1 = (const float*)d_in[4];
    const float* W2 = (const float*)d_in[5];
    const float* b2 = (const float*)d_in[6];
    const float* W3 = (const float*)d_in[7];
    const float* b3 = (const float*)d_in[8];

    const int M = 4096;
    const int K0 = 2048;
    const int D0 = 4096, D1 = 4096, D2 = 4096, D3 = 1024;

    // allow 128 KiB dynamic LDS — unconditional (host-side, capture-safe, idempotent)
    hipFuncSetAttribute(reinterpret_cast<const void*>(&gemm256<1, 1, 1, 1>),
                        hipFuncAttributeMaxDynamicSharedMemorySize, 131072);
    hipFuncSetAttribute(reinterpret_cast<const void*>(&gemm256<0, 0, 0, 4>),
                        hipFuncAttributeMaxDynamicSharedMemorySize, 131072);

    unsigned short* p = (unsigned short*)d_ws;
    unsigned short* xhi = p; p += (size_t)M * K0;
    unsigned short* xlo = p; p += (size_t)M * K0;
    unsigned short* whi = p; p += (size_t)D1 * D0;
    unsigned short* wlo = p; p += (size_t)D1 * D0;
    unsigned short* h0hi = p; p += (size_t)M * D0;
    unsigned short* h0lo = p; p += (size_t)M * D0;
    unsigned short* h1hi = p; p += (size_t)M * D1;
    unsigned short* h1lo = p; p += (size_t)M * D1;
    // L3 split-K partials: reuse dead h1 region (4 x M x D3 f32 = 67MB)
    float* part = (float*)h1hi;

    auto split = [&](const float* src, unsigned short* hi, unsigned short* lo, size_t n) {
        int n4 = (int)(n >> 2);
        split_kernel<<<(n4 + 255) / 256, 256, 0, stream>>>(src, hi, lo, n4);
    };

    // L0: h0 = relu(x @ W0^T + b0)   [4096 x 4096, K=2048]
    split(x, xhi, xlo, (size_t)M * K0);
    split(W0, whi, wlo, (size_t)D0 * K0);
    gemm256<1, 1, 1, 1><<<(M / 256) * (D0 / 256), 512, 131072, stream>>>(
        xhi, xlo, whi, wlo, b0, nullptr, h0hi, h0lo, M, D0, K0, K0);

    // L1: h1 = relu(h0 @ W1^T + b1)  [4096 x 4096, K=4096]
    split(W1, whi, wlo, (size_t)D1 * D0);
    gemm256<1, 1, 1, 1><<<(M / 256) * (D1 / 256), 512, 131072, stream>>>(
        h0hi, h0lo, whi, wlo, b1, nullptr, h1hi, h1lo, M, D1, D0, D0);

    // L2: h2 = relu(h1 @ W2^T + b2)  [4096 x 4096, K=4096]
    split(W2, whi, wlo, (size_t)D2 * D1);
    gemm256<1, 1, 1, 1><<<(M / 256) * (D2 / 256), 512, 131072, stream>>>(
        h1hi, h1lo, whi, wlo, b2, nullptr, h0hi, h0lo, M, D2, D1, D1);

    // L3: out = h2 @ W3^T + b3       [4096 x 1024, K=4096], split-K=4, fp32 out
    split(W3, whi, wlo, (size_t)D3 * D2);
    gemm256<0, 0, 0, 4><<<(M / 256) * (D3 / 256) * 4, 512, 131072, stream>>>(
        h0hi, h0lo, whi, wlo, b3, part, nullptr, nullptr, M, D3, D2, D2 / 4);
    {
        int n4 = M * D3 / 4;
        reduce4_bias<<<(n4 + 255) / 256, 256, 0, stream>>>(
            part, b3, (float*)d_out, n4, D3, (size_t)M * D3);
    }
}